// Round 1
// baseline (203.336 us; speedup 1.0000x reference)
//
#include <hip/hip_runtime.h>

// Problem: B=64, S=128, D_MODEL=D_INNER=1024  ->  M = B*S = 8192, K = N = 1024.
// Reference simplifies: numerator/denominator == v exactly (dw>0, exp_k>0 cancel),
// so out = (sigmoid(emb@Wq+bq) * (emb@Wv+bv)) @ Wo + bo.  Wk, bk, w are dead inputs.

typedef short bf16x8 __attribute__((ext_vector_type(8)));  // 8 bf16 = 4 VGPRs
typedef float f32x4  __attribute__((ext_vector_type(4)));

__device__ __forceinline__ short f2bf(float f) {  // RNE fp32 -> bf16
  union { float f; unsigned u; } x; x.f = f;
  unsigned r = x.u + 0x7fffu + ((x.u >> 16) & 1u);
  return (short)(r >> 16);
}
__device__ __forceinline__ float bf2f(short s) {
  union { float f; unsigned u; } x; x.u = ((unsigned)(unsigned short)s) << 16;
  return x.f;
}

struct alignas(16) S8 { short v[8]; };

// ---- fp32 -> bf16 straight cast, 8 elements/thread ----
__global__ void cvt_bf16_kernel(const float* __restrict__ in, short* __restrict__ out, int n8) {
  int i = blockIdx.x * blockDim.x + threadIdx.x;
  if (i >= n8) return;
  const float4* p = (const float4*)in + (size_t)i * 2;
  float4 a = p[0], b = p[1];
  S8 s;
  s.v[0] = f2bf(a.x); s.v[1] = f2bf(a.y); s.v[2] = f2bf(a.z); s.v[3] = f2bf(a.w);
  s.v[4] = f2bf(b.x); s.v[5] = f2bf(b.y); s.v[6] = f2bf(b.z); s.v[7] = f2bf(b.w);
  ((S8*)out)[i] = s;
}

// ---- transpose + cast: out[C][R] (bf16) = in[R][C] (fp32); R,C multiples of 32 ----
__global__ void transpose_cvt_kernel(const float* __restrict__ in, short* __restrict__ out,
                                     int R, int C) {
  __shared__ float tile[32][33];  // +1 pad: no bank conflicts
  int bx = blockIdx.x * 32;       // col tile of in
  int by = blockIdx.y * 32;       // row tile of in
  int tx = threadIdx.x & 31, ty = threadIdx.x >> 5;  // 256 threads: ty 0..7
#pragma unroll
  for (int i = 0; i < 32; i += 8)
    tile[ty + i][tx] = in[(size_t)(by + ty + i) * C + bx + tx];
  __syncthreads();
#pragma unroll
  for (int i = 0; i < 32; i += 8)
    out[(size_t)(bx + ty + i) * R + by + tx] = f2bf(tile[tx][ty + i]);
}

// ---- elementwise combine: X[m][n] = sigmoid(X2[m][n]+bq[n]) * (X2[m][1024+n]+bv[n]) ----
__global__ void combine_kernel(const short* __restrict__ X2, const float* __restrict__ bq,
                               const float* __restrict__ bv, short* __restrict__ X) {
  int i = blockIdx.x * blockDim.x + threadIdx.x;  // exactly 8192*1024/8 threads
  int row = i >> 7;
  int c = (i & 127) * 8;
  S8 q8 = *(const S8*)(X2 + (size_t)row * 2048 + c);
  S8 v8 = *(const S8*)(X2 + (size_t)row * 2048 + 1024 + c);
  float4 b0 = ((const float4*)(bq + c))[0], b1 = ((const float4*)(bq + c))[1];
  float4 c0 = ((const float4*)(bv + c))[0], c1 = ((const float4*)(bv + c))[1];
  float qb[8] = {b0.x, b0.y, b0.z, b0.w, b1.x, b1.y, b1.z, b1.w};
  float vb[8] = {c0.x, c0.y, c0.z, c0.w, c1.x, c1.y, c1.z, c1.w};
  S8 o;
#pragma unroll
  for (int j = 0; j < 8; j++) {
    float q = bf2f(q8.v[j]) + qb[j];
    float v = bf2f(v8.v[j]) + vb[j];
    float s = 1.0f / (1.0f + expf(-q));
    o.v[j] = f2bf(s * v);
  }
  *(S8*)(X + (size_t)row * 1024 + c) = o;
}

// ---- m97-style bf16 GEMM: C[M,N] = A[M,K] @ BT[N,K]^T (+bias) ----
// 128x128 block tile, BK=32, 4 waves each computing 64x64 (4x4 of 16x16x32 MFMA),
// global->LDS staging via global_load_lds width=16.
#define GLDS(g, l) \
  __builtin_amdgcn_global_load_lds((const __attribute__((address_space(1))) void*)(g), \
                                   (__attribute__((address_space(3))) void*)(l), 16, 0, 0)

template <int MODE>  // 0: bf16 store, no bias ; 1: fp32 store + bias
__global__ __launch_bounds__(256) void gemm_bt_kernel(
    const short* __restrict__ A, const short* __restrict__ BT, void* __restrict__ Cp,
    const float* __restrict__ bias, int N, int K) {
  __shared__ short As[128 * 32];  // [row][k] 8 KiB
  __shared__ short Bs[128 * 32];  // [col][k] 8 KiB
  const int t = threadIdx.x;
  const int lane = t & 63;
  const int w = t >> 6;
  const int bm = blockIdx.x * 128;
  const int bn = blockIdx.y * 128;
  const int wm = (w & 1) * 64;
  const int wn = (w >> 1) * 64;
  const int l16 = lane & 15;
  const int quad = lane >> 4;

  // staging: chunk c = inst*256 + t ; row = c>>2, k-offset = (c&3)*8
  const int r0 = t >> 2;
  const int qo = (t & 3) * 8;
  const short* gA0 = A + (size_t)(bm + r0) * K + qo;
  const short* gA1 = A + (size_t)(bm + 64 + r0) * K + qo;
  const short* gB0 = BT + (size_t)(bn + r0) * K + qo;
  const short* gB1 = BT + (size_t)(bn + 64 + r0) * K + qo;
  short* lA0 = As + w * 64 * 8;          // wave-uniform LDS bases; HW adds lane*16B
  short* lA1 = As + (256 + w * 64) * 8;
  short* lB0 = Bs + w * 64 * 8;
  short* lB1 = Bs + (256 + w * 64) * 8;

  f32x4 acc[4][4] = {};

  for (int k0 = 0; k0 < K; k0 += 32) {
    GLDS(gA0 + k0, lA0);
    GLDS(gA1 + k0, lA1);
    GLDS(gB0 + k0, lB0);
    GLDS(gB1 + k0, lB1);
    __syncthreads();  // drains vmcnt -> staging visible

    bf16x8 av[4], bw[4];
#pragma unroll
    for (int i = 0; i < 4; i++)
      av[i] = *(const bf16x8*)(As + (wm + i * 16 + l16) * 32 + quad * 8);
#pragma unroll
    for (int j = 0; j < 4; j++)
      bw[j] = *(const bf16x8*)(Bs + (wn + j * 16 + l16) * 32 + quad * 8);
#pragma unroll
    for (int i = 0; i < 4; i++)
#pragma unroll
      for (int j = 0; j < 4; j++)
        acc[i][j] = __builtin_amdgcn_mfma_f32_16x16x32_bf16(av[i], bw[j], acc[i][j], 0, 0, 0);
    __syncthreads();  // protect LDS before next stage overwrites
  }

  // epilogue: C/D layout col=lane&15, row=(lane>>4)*4+reg  [m89/m91-verified]
#pragma unroll
  for (int i = 0; i < 4; i++)
#pragma unroll
    for (int j = 0; j < 4; j++)
#pragma unroll
      for (int r = 0; r < 4; r++) {
        int row = bm + wm + i * 16 + quad * 4 + r;
        int col = bn + wn + j * 16 + l16;
        if (MODE == 0)
          ((short*)Cp)[(size_t)row * N + col] = f2bf(acc[i][j][r]);
        else
          ((float*)Cp)[(size_t)row * N + col] = acc[i][j][r] + bias[col];
      }
}

extern "C" void kernel_launch(void* const* d_in, const int* in_sizes, int n_in,
                              void* d_out, int out_size, void* d_ws, size_t ws_size,
                              hipStream_t stream) {
  const float* emb = (const float*)d_in[0];
  const float* Wq  = (const float*)d_in[1];
  const float* bq  = (const float*)d_in[2];
  // d_in[3]=Wk, d_in[4]=bk, d_in[7]=w are mathematically dead (they cancel)
  const float* Wv  = (const float*)d_in[5];
  const float* bv  = (const float*)d_in[6];
  const float* Wo  = (const float*)d_in[8];
  const float* bo  = (const float*)d_in[9];
  float* out = (float*)d_out;

  // workspace layout (bytes); X aliases embB (embB dead once GEMM1 completes)
  char* ws = (char*)d_ws;
  short* embB = (short*)(ws);                 // 8192*1024 bf16 = 16.0 MiB
  short* X    = (short*)(ws);                 // alias of embB region
  short* X2   = (short*)(ws + 16777216);      // 8192*2048 bf16 = 32.0 MiB
  short* WqvT = (short*)(ws + 50331648);      // [WqT | WvT] 2048*1024 = 4.0 MiB
  short* WoT  = (short*)(ws + 54525952);      // 1024*1024 = 2.0 MiB
  // total: 56,623,104 bytes

  cvt_bf16_kernel<<<4096, 256, 0, stream>>>(emb, embB, 1048576);
  transpose_cvt_kernel<<<dim3(32, 32), 256, 0, stream>>>(Wq, WqvT, 1024, 1024);
  transpose_cvt_kernel<<<dim3(32, 32), 256, 0, stream>>>(Wv, WqvT + 1024 * 1024, 1024, 1024);
  transpose_cvt_kernel<<<dim3(32, 32), 256, 0, stream>>>(Wo, WoT, 1024, 1024);

  // X2[8192, 2048] = embB @ [Wq | Wv]
  gemm_bt_kernel<0><<<dim3(64, 16), 256, 0, stream>>>(embB, WqvT, (void*)X2, nullptr, 2048, 1024);
  // X = sigmoid(q+bq) * (v+bv)
  combine_kernel<<<4096, 256, 0, stream>>>(X2, bq, bv, X);
  // out[8192, 1024] = X @ Wo + bo
  gemm_bt_kernel<1><<<dim3(64, 8), 256, 0, stream>>>(X, WoT, (void*)out, bo, 1024, 1024);
}

// Round 2
// 194.763 us; speedup vs baseline: 1.0440x; 1.0440x over previous
//
#include <hip/hip_runtime.h>

// Problem: B=64, S=128, D_MODEL=D_INNER=1024  ->  M = B*S = 8192, K = N = 1024.
// Reference simplifies: numerator/denominator == v exactly (dw>0, exp_k>0 cancel),
// so out = (sigmoid(emb@Wq+bq) * (emb@Wv+bv)) @ Wo + bo.  Wk, bk, w are dead inputs.
//
// R2: fuse sigmoid-combine into GEMM1 (dual q|v accumulation per block), merge the
// three weight transposes into one launch. 4 dispatches total.

typedef short bf16x8 __attribute__((ext_vector_type(8)));  // 8 bf16 = 4 VGPRs
typedef float f32x4  __attribute__((ext_vector_type(4)));

__device__ __forceinline__ short f2bf(float f) {  // RNE fp32 -> bf16
  union { float f; unsigned u; } x; x.f = f;
  unsigned r = x.u + 0x7fffu + ((x.u >> 16) & 1u);
  return (short)(r >> 16);
}

struct alignas(16) S8 { short v[8]; };

// ---- fp32 -> bf16 straight cast, 8 elements/thread ----
__global__ void cvt_bf16_kernel(const float* __restrict__ in, short* __restrict__ out, int n8) {
  int i = blockIdx.x * blockDim.x + threadIdx.x;
  if (i >= n8) return;
  const float4* p = (const float4*)in + (size_t)i * 2;
  float4 a = p[0], b = p[1];
  S8 s;
  s.v[0] = f2bf(a.x); s.v[1] = f2bf(a.y); s.v[2] = f2bf(a.z); s.v[3] = f2bf(a.w);
  s.v[4] = f2bf(b.x); s.v[5] = f2bf(b.y); s.v[6] = f2bf(b.z); s.v[7] = f2bf(b.w);
  ((S8*)out)[i] = s;
}

// ---- transpose + cast for the three 1024x1024 weights, z-indexed ----
__global__ void transpose3_kernel(const float* __restrict__ Wq, const float* __restrict__ Wv,
                                  const float* __restrict__ Wo, short* __restrict__ WqvT,
                                  short* __restrict__ WoT) {
  const int RC = 1024;
  const float* in; short* out;
  if (blockIdx.z == 0)      { in = Wq; out = WqvT; }
  else if (blockIdx.z == 1) { in = Wv; out = WqvT + 1024 * 1024; }
  else                      { in = Wo; out = WoT; }
  __shared__ float tile[32][33];  // +1 pad: no bank conflicts
  int bx = blockIdx.x * 32;
  int by = blockIdx.y * 32;
  int tx = threadIdx.x & 31, ty = threadIdx.x >> 5;  // 256 threads: ty 0..7
#pragma unroll
  for (int i = 0; i < 32; i += 8)
    tile[ty + i][tx] = in[(size_t)(by + ty + i) * RC + bx + tx];
  __syncthreads();
#pragma unroll
  for (int i = 0; i < 32; i += 8)
    out[(size_t)(bx + ty + i) * RC + by + tx] = f2bf(tile[tx][ty + i]);
}

#define GLDS(g, l) \
  __builtin_amdgcn_global_load_lds((const __attribute__((address_space(1))) void*)(g), \
                                   (__attribute__((address_space(3))) void*)(l), 16, 0, 0)

// ---- fused GEMM1: X[m][c] = sigmoid(A@WqT + bq) * (A@WvT + bv), bf16 out ----
// Block tile: 128 rows x 64 cols, dual q|v accumulators. 4 waves: each 64x32 per side.
// grid (M/128, 1024/64) = (64, 16) = 1024 blocks.
__global__ __launch_bounds__(256) void gemm_qv_kernel(
    const short* __restrict__ A, const short* __restrict__ BT,  // BT = [WqT | WvT], 2048 x 1024
    const float* __restrict__ bq, const float* __restrict__ bv,
    short* __restrict__ X, int K) {
  __shared__ short As[128 * 32];  // 8 KiB
  __shared__ short Bq[64 * 32];   // 4 KiB
  __shared__ short Bv[64 * 32];   // 4 KiB
  const int t = threadIdx.x;
  const int lane = t & 63;
  const int w = t >> 6;
  const int bm = blockIdx.x * 128;
  const int bn = blockIdx.y * 64;
  const int wm = (w & 1) * 64;
  const int wn = (w >> 1) * 32;
  const int l16 = lane & 15;
  const int quad = lane >> 4;

  // staging: chunk index c = t (+64/128/192 per instr); row = c>>2, k-off = (c&3)*8
  const int r0 = t >> 2;          // 0..63
  const int qo = (t & 3) * 8;
  const short* gA0 = A + (size_t)(bm + r0) * K + qo;
  const short* gA1 = A + (size_t)(bm + 64 + r0) * K + qo;
  const short* gBq = BT + (size_t)(bn + r0) * K + qo;           // q cols: rows bn..bn+63
  const short* gBv = BT + (size_t)(1024 + bn + r0) * K + qo;    // v cols
  short* lA0 = As + w * 512;       // wave-uniform LDS bases; HW adds lane*16B
  short* lA1 = As + 2048 + w * 512;
  short* lBq = Bq + w * 512;
  short* lBv = Bv + w * 512;

  f32x4 accq[4][2] = {};
  f32x4 accv[4][2] = {};

  for (int k0 = 0; k0 < K; k0 += 32) {
    GLDS(gA0 + k0, lA0);
    GLDS(gA1 + k0, lA1);
    GLDS(gBq + k0, lBq);
    GLDS(gBv + k0, lBv);
    __syncthreads();

    bf16x8 av[4], bqf[2], bvf[2];
#pragma unroll
    for (int i = 0; i < 4; i++)
      av[i] = *(const bf16x8*)(As + (wm + i * 16 + l16) * 32 + quad * 8);
#pragma unroll
    for (int j = 0; j < 2; j++) {
      bqf[j] = *(const bf16x8*)(Bq + (wn + j * 16 + l16) * 32 + quad * 8);
      bvf[j] = *(const bf16x8*)(Bv + (wn + j * 16 + l16) * 32 + quad * 8);
    }
#pragma unroll
    for (int i = 0; i < 4; i++)
#pragma unroll
      for (int j = 0; j < 2; j++) {
        accq[i][j] = __builtin_amdgcn_mfma_f32_16x16x32_bf16(av[i], bqf[j], accq[i][j], 0, 0, 0);
        accv[i][j] = __builtin_amdgcn_mfma_f32_16x16x32_bf16(av[i], bvf[j], accv[i][j], 0, 0, 0);
      }
    __syncthreads();
  }

  // epilogue: C/D layout col=lane&15, row=(lane>>4)*4+reg  [m89/m91-verified]
#pragma unroll
  for (int j = 0; j < 2; j++) {
    int col = bn + wn + j * 16 + l16;
    float bql = bq[col], bvl = bv[col];
#pragma unroll
    for (int i = 0; i < 4; i++)
#pragma unroll
      for (int r = 0; r < 4; r++) {
        int row = bm + wm + i * 16 + quad * 4 + r;
        float q = accq[i][j][r] + bql;
        float v = accv[i][j][r] + bvl;
        float s = 1.0f / (1.0f + __expf(-q));
        X[(size_t)row * 1024 + col] = f2bf(s * v);
      }
  }
}

// ---- GEMM2: out[M,N] = X[M,K] @ WoT[N,K]^T + bo, fp32 out (m97 structure) ----
__global__ __launch_bounds__(256) void gemm_bt_kernel(
    const short* __restrict__ A, const short* __restrict__ BT, float* __restrict__ C,
    const float* __restrict__ bias, int N, int K) {
  __shared__ short As[128 * 32];  // 8 KiB
  __shared__ short Bs[128 * 32];  // 8 KiB
  const int t = threadIdx.x;
  const int lane = t & 63;
  const int w = t >> 6;
  const int bm = blockIdx.x * 128;
  const int bn = blockIdx.y * 128;
  const int wm = (w & 1) * 64;
  const int wn = (w >> 1) * 64;
  const int l16 = lane & 15;
  const int quad = lane >> 4;

  const int r0 = t >> 2;
  const int qo = (t & 3) * 8;
  const short* gA0 = A + (size_t)(bm + r0) * K + qo;
  const short* gA1 = A + (size_t)(bm + 64 + r0) * K + qo;
  const short* gB0 = BT + (size_t)(bn + r0) * K + qo;
  const short* gB1 = BT + (size_t)(bn + 64 + r0) * K + qo;
  short* lA0 = As + w * 512;
  short* lA1 = As + 2048 + w * 512;
  short* lB0 = Bs + w * 512;
  short* lB1 = Bs + 2048 + w * 512;

  f32x4 acc[4][4] = {};

  for (int k0 = 0; k0 < K; k0 += 32) {
    GLDS(gA0 + k0, lA0);
    GLDS(gA1 + k0, lA1);
    GLDS(gB0 + k0, lB0);
    GLDS(gB1 + k0, lB1);
    __syncthreads();

    bf16x8 av[4], bw[4];
#pragma unroll
    for (int i = 0; i < 4; i++)
      av[i] = *(const bf16x8*)(As + (wm + i * 16 + l16) * 32 + quad * 8);
#pragma unroll
    for (int j = 0; j < 4; j++)
      bw[j] = *(const bf16x8*)(Bs + (wn + j * 16 + l16) * 32 + quad * 8);
#pragma unroll
    for (int i = 0; i < 4; i++)
#pragma unroll
      for (int j = 0; j < 4; j++)
        acc[i][j] = __builtin_amdgcn_mfma_f32_16x16x32_bf16(av[i], bw[j], acc[i][j], 0, 0, 0);
    __syncthreads();
  }

#pragma unroll
  for (int j = 0; j < 4; j++) {
    int col = bn + wn + j * 16 + l16;
    float bl = bias[col];
#pragma unroll
    for (int i = 0; i < 4; i++)
#pragma unroll
      for (int r = 0; r < 4; r++) {
        int row = bm + wm + i * 16 + quad * 4 + r;
        C[(size_t)row * N + col] = acc[i][j][r] + bl;
      }
  }
}

extern "C" void kernel_launch(void* const* d_in, const int* in_sizes, int n_in,
                              void* d_out, int out_size, void* d_ws, size_t ws_size,
                              hipStream_t stream) {
  const float* emb = (const float*)d_in[0];
  const float* Wq  = (const float*)d_in[1];
  const float* bq  = (const float*)d_in[2];
  // d_in[3]=Wk, d_in[4]=bk, d_in[7]=w are mathematically dead (they cancel)
  const float* Wv  = (const float*)d_in[5];
  const float* bv  = (const float*)d_in[6];
  const float* Wo  = (const float*)d_in[8];
  const float* bo  = (const float*)d_in[9];
  float* out = (float*)d_out;

  // workspace layout (bytes). X may NOT alias embB now (GEMM1 writes X while
  // other blocks still read embB).
  char* ws = (char*)d_ws;
  short* embB = (short*)(ws);                 // 8192*1024 bf16 = 16 MiB
  short* X    = (short*)(ws + 16777216);      // 8192*1024 bf16 = 16 MiB
  short* WqvT = (short*)(ws + 33554432);      // [WqT | WvT] 2048*1024 = 4 MiB
  short* WoT  = (short*)(ws + 37748736);      // 1024*1024 = 2 MiB
  // total: 39,845,888 bytes

  cvt_bf16_kernel<<<4096, 256, 0, stream>>>(emb, embB, 1048576);
  transpose3_kernel<<<dim3(32, 32, 3), 256, 0, stream>>>(Wq, Wv, Wo, WqvT, WoT);

  // X = sigmoid(embB@WqT + bq) * (embB@WvT + bv)   [fused]
  gemm_qv_kernel<<<dim3(64, 16), 256, 0, stream>>>(embB, WqvT, bq, bv, X, 1024);
  // out = X @ WoT^T + bo
  gemm_bt_kernel<<<dim3(64, 8), 256, 0, stream>>>(X, WoT, out, bo, 1024, 1024);
}

// Round 3
// 189.139 us; speedup vs baseline: 1.0751x; 1.0297x over previous
//
#include <hip/hip_runtime.h>

// Problem: B=64, S=128, D_MODEL=D_INNER=1024  ->  M = B*S = 8192, K = N = 1024.
// Reference simplifies: numerator/denominator == v exactly (dw>0, exp_k>0 cancel),
// so out = (sigmoid(emb@Wq+bq) * (emb@Wv+bv)) @ Wo + bo.  Wk, bk, w are dead inputs.
//
// R3: (a) XOR-swizzle LDS K-chunks to kill ds_read_b128 bank conflicts (4.19M -> ~0);
//     (b) GEMM2 tile 128x64, grid 1024 blocks (was 512 = 2/CU latency-starved).
// Swizzle: 16B chunk j of row r stored at slot j ^ ((r>>1)&3). GLDS forces linear
// LDS destinations, so the permutation is applied on the global gather side.

typedef short bf16x8 __attribute__((ext_vector_type(8)));  // 8 bf16 = 4 VGPRs
typedef float f32x4  __attribute__((ext_vector_type(4)));

__device__ __forceinline__ short f2bf(float f) {  // RNE fp32 -> bf16
  union { float f; unsigned u; } x; x.f = f;
  unsigned r = x.u + 0x7fffu + ((x.u >> 16) & 1u);
  return (short)(r >> 16);
}

struct alignas(16) S8 { short v[8]; };

// ---- fp32 -> bf16 straight cast, 8 elements/thread ----
__global__ void cvt_bf16_kernel(const float* __restrict__ in, short* __restrict__ out, int n8) {
  int i = blockIdx.x * blockDim.x + threadIdx.x;
  if (i >= n8) return;
  const float4* p = (const float4*)in + (size_t)i * 2;
  float4 a = p[0], b = p[1];
  S8 s;
  s.v[0] = f2bf(a.x); s.v[1] = f2bf(a.y); s.v[2] = f2bf(a.z); s.v[3] = f2bf(a.w);
  s.v[4] = f2bf(b.x); s.v[5] = f2bf(b.y); s.v[6] = f2bf(b.z); s.v[7] = f2bf(b.w);
  ((S8*)out)[i] = s;
}

// ---- transpose + cast for the three 1024x1024 weights, z-indexed ----
__global__ void transpose3_kernel(const float* __restrict__ Wq, const float* __restrict__ Wv,
                                  const float* __restrict__ Wo, short* __restrict__ WqvT,
                                  short* __restrict__ WoT) {
  const int RC = 1024;
  const float* in; short* out;
  if (blockIdx.z == 0)      { in = Wq; out = WqvT; }
  else if (blockIdx.z == 1) { in = Wv; out = WqvT + 1024 * 1024; }
  else                      { in = Wo; out = WoT; }
  __shared__ float tile[32][33];  // +1 pad: no bank conflicts
  int bx = blockIdx.x * 32;
  int by = blockIdx.y * 32;
  int tx = threadIdx.x & 31, ty = threadIdx.x >> 5;  // 256 threads: ty 0..7
#pragma unroll
  for (int i = 0; i < 32; i += 8)
    tile[ty + i][tx] = in[(size_t)(by + ty + i) * RC + bx + tx];
  __syncthreads();
#pragma unroll
  for (int i = 0; i < 32; i += 8)
    out[(size_t)(bx + ty + i) * RC + by + tx] = f2bf(tile[tx][ty + i]);
}

#define GLDS(g, l) \
  __builtin_amdgcn_global_load_lds((const __attribute__((address_space(1))) void*)(g), \
                                   (__attribute__((address_space(3))) void*)(l), 16, 0, 0)

// ---- fused GEMM1: X[m][c] = sigmoid(A@WqT + bq) * (A@WvT + bv), bf16 out ----
// Block tile: 128 rows x 64 cols, dual q|v accumulators. 4 waves: each 64x32 per side.
// grid (M/128, 1024/64) = (64, 16) = 1024 blocks.
__global__ __launch_bounds__(256) void gemm_qv_kernel(
    const short* __restrict__ A, const short* __restrict__ BT,  // BT = [WqT | WvT], 2048 x 1024
    const float* __restrict__ bq, const float* __restrict__ bv,
    short* __restrict__ X, int K) {
  __shared__ short As[128 * 32];  // 8 KiB
  __shared__ short Bq[64 * 32];   // 4 KiB
  __shared__ short Bv[64 * 32];   // 4 KiB
  const int t = threadIdx.x;
  const int lane = t & 63;
  const int w = t >> 6;
  const int bm = blockIdx.x * 128;
  const int bn = blockIdx.y * 64;
  const int wm = (w & 1) * 64;
  const int wn = (w >> 1) * 32;
  const int l16 = lane & 15;
  const int quad = lane >> 4;

  // staging (swizzled gather): chunk c = inst*256 + t; row = c>>2, slot = c&3 holds
  // data chunk (slot ^ ((row>>1)&3)). 64 B rows: swizzle stays in-row -> coalesced.
  const int r0 = t >> 2;          // 0..63 (row within 64-row group; +64 keeps swizzle)
  const int qo = (((t & 3) ^ ((r0 >> 1) & 3)) * 8);
  const short* gA0 = A + (size_t)(bm + r0) * K + qo;
  const short* gA1 = A + (size_t)(bm + 64 + r0) * K + qo;
  const short* gBq = BT + (size_t)(bn + r0) * K + qo;           // q cols: rows bn..bn+63
  const short* gBv = BT + (size_t)(1024 + bn + r0) * K + qo;    // v cols
  short* lA0 = As + w * 512;       // wave-uniform LDS bases; HW adds lane*16B
  short* lA1 = As + 2048 + w * 512;
  short* lBq = Bq + w * 512;
  short* lBv = Bv + w * 512;

  // fragment-read swizzle: row = (16-mult) + l16 -> s = (l16>>1)&3 only
  const int qs = ((quad ^ ((l16 >> 1) & 3)) * 8);

  f32x4 accq[4][2] = {};
  f32x4 accv[4][2] = {};

  for (int k0 = 0; k0 < K; k0 += 32) {
    GLDS(gA0 + k0, lA0);
    GLDS(gA1 + k0, lA1);
    GLDS(gBq + k0, lBq);
    GLDS(gBv + k0, lBv);
    __syncthreads();

    bf16x8 av[4], bqf[2], bvf[2];
#pragma unroll
    for (int i = 0; i < 4; i++)
      av[i] = *(const bf16x8*)(As + (wm + i * 16 + l16) * 32 + qs);
#pragma unroll
    for (int j = 0; j < 2; j++) {
      bqf[j] = *(const bf16x8*)(Bq + (wn + j * 16 + l16) * 32 + qs);
      bvf[j] = *(const bf16x8*)(Bv + (wn + j * 16 + l16) * 32 + qs);
    }
#pragma unroll
    for (int i = 0; i < 4; i++)
#pragma unroll
      for (int j = 0; j < 2; j++) {
        accq[i][j] = __builtin_amdgcn_mfma_f32_16x16x32_bf16(av[i], bqf[j], accq[i][j], 0, 0, 0);
        accv[i][j] = __builtin_amdgcn_mfma_f32_16x16x32_bf16(av[i], bvf[j], accv[i][j], 0, 0, 0);
      }
    __syncthreads();
  }

  // epilogue: C/D layout col=lane&15, row=(lane>>4)*4+reg  [m89/m91-verified]
#pragma unroll
  for (int j = 0; j < 2; j++) {
    int col = bn + wn + j * 16 + l16;
    float bql = bq[col], bvl = bv[col];
#pragma unroll
    for (int i = 0; i < 4; i++)
#pragma unroll
      for (int r = 0; r < 4; r++) {
        int row = bm + wm + i * 16 + quad * 4 + r;
        float q = accq[i][j][r] + bql;
        float v = accv[i][j][r] + bvl;
        float s = 1.0f / (1.0f + __expf(-q));
        X[(size_t)row * 1024 + col] = f2bf(s * v);
      }
  }
}

// ---- GEMM2: out[M,N] = X[M,K] @ WoT[N,K]^T + bo, fp32 out ----
// R3: 128x64 tile -> grid (64,16) = 1024 blocks (4/CU). Waves: 64x32 each.
__global__ __launch_bounds__(256) void gemm_bt_kernel(
    const short* __restrict__ A, const short* __restrict__ BT, float* __restrict__ C,
    const float* __restrict__ bias, int N, int K) {
  __shared__ short As[128 * 32];  // 8 KiB
  __shared__ short Bs[64 * 32];   // 4 KiB
  const int t = threadIdx.x;
  const int lane = t & 63;
  const int w = t >> 6;
  const int bm = blockIdx.x * 128;
  const int bn = blockIdx.y * 64;
  const int wm = (w & 1) * 64;
  const int wn = (w >> 1) * 32;
  const int l16 = lane & 15;
  const int quad = lane >> 4;

  const int r0 = t >> 2;
  const int qo = (((t & 3) ^ ((r0 >> 1) & 3)) * 8);
  const short* gA0 = A + (size_t)(bm + r0) * K + qo;
  const short* gA1 = A + (size_t)(bm + 64 + r0) * K + qo;
  const short* gB0 = BT + (size_t)(bn + r0) * K + qo;
  short* lA0 = As + w * 512;
  short* lA1 = As + 2048 + w * 512;
  short* lB0 = Bs + w * 512;

  const int qs = ((quad ^ ((l16 >> 1) & 3)) * 8);

  f32x4 acc[4][2] = {};

  for (int k0 = 0; k0 < K; k0 += 32) {
    GLDS(gA0 + k0, lA0);
    GLDS(gA1 + k0, lA1);
    GLDS(gB0 + k0, lB0);
    __syncthreads();

    bf16x8 av[4], bw[2];
#pragma unroll
    for (int i = 0; i < 4; i++)
      av[i] = *(const bf16x8*)(As + (wm + i * 16 + l16) * 32 + qs);
#pragma unroll
    for (int j = 0; j < 2; j++)
      bw[j] = *(const bf16x8*)(Bs + (wn + j * 16 + l16) * 32 + qs);
#pragma unroll
    for (int i = 0; i < 4; i++)
#pragma unroll
      for (int j = 0; j < 2; j++)
        acc[i][j] = __builtin_amdgcn_mfma_f32_16x16x32_bf16(av[i], bw[j], acc[i][j], 0, 0, 0);
    __syncthreads();
  }

#pragma unroll
  for (int j = 0; j < 2; j++) {
    int col = bn + wn + j * 16 + l16;
    float bl = bias[col];
#pragma unroll
    for (int i = 0; i < 4; i++)
#pragma unroll
      for (int r = 0; r < 4; r++) {
        int row = bm + wm + i * 16 + quad * 4 + r;
        C[(size_t)row * N + col] = acc[i][j][r] + bl;
      }
  }
}

extern "C" void kernel_launch(void* const* d_in, const int* in_sizes, int n_in,
                              void* d_out, int out_size, void* d_ws, size_t ws_size,
                              hipStream_t stream) {
  const float* emb = (const float*)d_in[0];
  const float* Wq  = (const float*)d_in[1];
  const float* bq  = (const float*)d_in[2];
  // d_in[3]=Wk, d_in[4]=bk, d_in[7]=w are mathematically dead (they cancel)
  const float* Wv  = (const float*)d_in[5];
  const float* bv  = (const float*)d_in[6];
  const float* Wo  = (const float*)d_in[8];
  const float* bo  = (const float*)d_in[9];
  float* out = (float*)d_out;

  // workspace layout (bytes). X may NOT alias embB (GEMM1 writes X while
  // other blocks still read embB).
  char* ws = (char*)d_ws;
  short* embB = (short*)(ws);                 // 8192*1024 bf16 = 16 MiB
  short* X    = (short*)(ws + 16777216);      // 8192*1024 bf16 = 16 MiB
  short* WqvT = (short*)(ws + 33554432);      // [WqT | WvT] 2048*1024 = 4 MiB
  short* WoT  = (short*)(ws + 37748736);      // 1024*1024 = 2 MiB
  // total: 39,845,888 bytes

  cvt_bf16_kernel<<<4096, 256, 0, stream>>>(emb, embB, 1048576);
  transpose3_kernel<<<dim3(32, 32, 3), 256, 0, stream>>>(Wq, Wv, Wo, WqvT, WoT);

  // X = sigmoid(embB@WqT + bq) * (embB@WvT + bv)   [fused]
  gemm_qv_kernel<<<dim3(64, 16), 256, 0, stream>>>(embB, WqvT, bq, bv, X, 1024);
  // out = X @ WoT^T + bo
  gemm_bt_kernel<<<dim3(64, 16), 256, 0, stream>>>(X, WoT, out, bo, 1024, 1024);
}

// Round 5
// 170.245 us; speedup vs baseline: 1.1944x; 1.1110x over previous
//
#include <hip/hip_runtime.h>

// Problem: B=64, S=128, D_MODEL=D_INNER=1024  ->  M = B*S = 8192, K = N = 1024.
// Reference simplifies: numerator/denominator == v exactly (dw>0, exp_k>0 cancel),
// so out = (sigmoid(emb@Wq+bq) * (emb@Wv+bv)) @ Wo + bo.  Wk, bk, w are dead inputs.
//
// R5: cooperative launch abandoned (R4 rejected: ~150 unified regs -> 3 blocks/CU ->
// max 768 co-resident < 1024; and R1-R3 timeline shows ~45-50us fixed replay overhead,
// so dispatch fusion isn't the lever). This round: R4's BK=64 GEMM bodies (half the
// vmcnt(0)+s_barrier drains vs BK=32) as 3 REGULAR launches, + manual pointer bumps
// and loop-invariant LDS fragment bases to cut the 49% VALUBusy address math.
// LDS swizzle (BK=64, 128B rows): slot' = slot ^ (row&7) -> all 8 bank groups x 8
// lanes = 2-way only = conflict-free (m136).

typedef short bf16x8 __attribute__((ext_vector_type(8)));  // 8 bf16 = 4 VGPRs
typedef float f32x4  __attribute__((ext_vector_type(4)));

__device__ __forceinline__ short f2bf(float f) {  // RNE fp32 -> bf16
  union { float f; unsigned u; } x; x.f = f;
  unsigned r = x.u + 0x7fffu + ((x.u >> 16) & 1u);
  return (short)(r >> 16);
}

struct alignas(16) S8 { short v[8]; };

#define GLDS(g, l) \
  __builtin_amdgcn_global_load_lds((const __attribute__((address_space(1))) void*)(g), \
                                   (__attribute__((address_space(3))) void*)(l), 16, 0, 0)

// ---- Phase 0: emb fp32->bf16 + transpose/cast the three 1024x1024 weights ----
__global__ __launch_bounds__(256) void prep_kernel(
    const float* __restrict__ emb, const float* __restrict__ Wq, const float* __restrict__ Wv,
    const float* __restrict__ Wo, short* __restrict__ embB, short* __restrict__ WqvT,
    short* __restrict__ WoT) {
  __shared__ float tr[32 * 33];
  const int t = threadIdx.x;
  const int bid = blockIdx.x;
  const int gdim = gridDim.x;

  // emb cast: 1048576 groups of 8
  for (size_t i = (size_t)bid * 256 + t; i < 1048576; i += (size_t)gdim * 256) {
    const float4* p = (const float4*)emb + i * 2;
    float4 a = p[0], b = p[1];
    S8 s;
    s.v[0] = f2bf(a.x); s.v[1] = f2bf(a.y); s.v[2] = f2bf(a.z); s.v[3] = f2bf(a.w);
    s.v[4] = f2bf(b.x); s.v[5] = f2bf(b.y); s.v[6] = f2bf(b.z); s.v[7] = f2bf(b.w);
    ((S8*)embB)[i] = s;
  }

  // weight transposes: 3*1024 = 3072 32x32 tiles
  int tx = t & 31, ty = t >> 5;
  for (int z = bid; z < 3072; z += gdim) {
    const float* in = (z < 1024) ? Wq : (z < 2048) ? Wv : Wo;
    short* op = (z < 1024) ? WqvT : (z < 2048) ? (WqvT + 1048576) : WoT;
    int ti = z & 1023;
    int bx = (ti & 31) * 32, by = (ti >> 5) * 32;
    __syncthreads();  // protect LDS reuse across loop iterations
#pragma unroll
    for (int i = 0; i < 32; i += 8)
      tr[(ty + i) * 33 + tx] = in[(size_t)(by + ty + i) * 1024 + bx + tx];
    __syncthreads();
#pragma unroll
    for (int i = 0; i < 32; i += 8)
      op[(size_t)(bx + ty + i) * 1024 + by + tx] = f2bf(tr[tx * 33 + ty + i]);
  }
}

// ---- Phase 1: X = sigmoid(embB@WqT+bq) * (embB@WvT+bv), bf16. BK=64. ----
// Block 128x64, 4 waves of 64x32 (q and v). grid (64,16)=1024.
__global__ __launch_bounds__(256) void gemm_qv_kernel(
    const short* __restrict__ A, const short* __restrict__ BT,  // BT=[WqT|WvT] 2048x1024
    const float* __restrict__ bq, const float* __restrict__ bv, short* __restrict__ X) {
  __shared__ short As[128 * 64];  // 16 KiB
  __shared__ short Bqs[64 * 64];  // 8 KiB
  __shared__ short Bvs[64 * 64];  // 8 KiB
  const int t = threadIdx.x;
  const int lane = t & 63;
  const int w = t >> 6;
  const int l16 = lane & 15;
  const int quad = lane >> 4;
  const int bm = blockIdx.x * 128;
  const int bn = blockIdx.y * 64;
  const int wm = (w & 1) * 64;
  const int wn = (w >> 1) * 32;

  // staging: per instr 256 lanes cover 32 rows x 128B; row=t>>3, slot=t&7,
  // slot holds global chunk slot^(row&7)
  const int r8 = t >> 3;
  const int swe = ((t & 7) ^ (r8 & 7)) * 8;
  const short* pA0 = A + (size_t)(bm + r8) * 1024 + swe;
  const short* pA1 = pA0 + 32 * 1024;
  const short* pA2 = pA0 + 64 * 1024;
  const short* pA3 = pA0 + 96 * 1024;
  const short* pBq0 = BT + (size_t)(bn + r8) * 1024 + swe;
  const short* pBq1 = pBq0 + 32 * 1024;
  const short* pBv0 = BT + (size_t)(1024 + bn + r8) * 1024 + swe;
  const short* pBv1 = pBv0 + 32 * 1024;
  short* lA = As + w * 512;    // wave-uniform; HW adds lane*16B
  short* lBq = Bqs + w * 512;
  short* lBv = Bvs + w * 512;

  // loop-invariant fragment bases (ds_read imm offsets handle i*1024 shorts)
  const int qsw0 = (quad ^ (l16 & 7)) * 8;        // k-half 0: chunk quad
  const int qsw1 = ((quad + 4) ^ (l16 & 7)) * 8;  // k-half 1: chunk quad+4
  const short* fA0 = As + (wm + l16) * 64 + qsw0;
  const short* fA1 = As + (wm + l16) * 64 + qsw1;
  const short* fq0 = Bqs + (wn + l16) * 64 + qsw0;
  const short* fq1 = Bqs + (wn + l16) * 64 + qsw1;
  const short* fv0 = Bvs + (wn + l16) * 64 + qsw0;
  const short* fv1 = Bvs + (wn + l16) * 64 + qsw1;

  f32x4 accq[4][2] = {};
  f32x4 accv[4][2] = {};

  for (int it = 0; it < 16; ++it) {
    GLDS(pA0, lA); GLDS(pA1, lA + 2048); GLDS(pA2, lA + 4096); GLDS(pA3, lA + 6144);
    GLDS(pBq0, lBq); GLDS(pBq1, lBq + 2048);
    GLDS(pBv0, lBv); GLDS(pBv1, lBv + 2048);
    pA0 += 64; pA1 += 64; pA2 += 64; pA3 += 64;
    pBq0 += 64; pBq1 += 64; pBv0 += 64; pBv1 += 64;
    __syncthreads();

#pragma unroll
    for (int h = 0; h < 2; h++) {
      const short* fA = h ? fA1 : fA0;
      const short* fq = h ? fq1 : fq0;
      const short* fv = h ? fv1 : fv0;
      bf16x8 av[4], bqf[2], bvf[2];
#pragma unroll
      for (int i = 0; i < 4; i++) av[i] = *(const bf16x8*)(fA + i * 1024);
#pragma unroll
      for (int j = 0; j < 2; j++) {
        bqf[j] = *(const bf16x8*)(fq + j * 1024);
        bvf[j] = *(const bf16x8*)(fv + j * 1024);
      }
#pragma unroll
      for (int i = 0; i < 4; i++)
#pragma unroll
        for (int j = 0; j < 2; j++) {
          accq[i][j] = __builtin_amdgcn_mfma_f32_16x16x32_bf16(av[i], bqf[j], accq[i][j], 0, 0, 0);
          accv[i][j] = __builtin_amdgcn_mfma_f32_16x16x32_bf16(av[i], bvf[j], accv[i][j], 0, 0, 0);
        }
    }
    __syncthreads();
  }

  // epilogue: C/D layout col=lane&15, row=(lane>>4)*4+reg  [m89/m91-verified]
#pragma unroll
  for (int j = 0; j < 2; j++) {
    int col = bn + wn + j * 16 + l16;
    float bql = bq[col], bvl = bv[col];
#pragma unroll
    for (int i = 0; i < 4; i++)
#pragma unroll
      for (int r = 0; r < 4; r++) {
        int row = bm + wm + i * 16 + quad * 4 + r;
        float q = accq[i][j][r] + bql;
        float v = accv[i][j][r] + bvl;
        float s = 1.0f / (1.0f + __expf(-q));
        X[(size_t)row * 1024 + col] = f2bf(s * v);
      }
  }
}

// ---- Phase 2: out = X @ WoT^T + bo, fp32. BK=64, block 128x64, grid (64,16). ----
__global__ __launch_bounds__(256) void gemm_bt_kernel(
    const short* __restrict__ A, const short* __restrict__ BT, float* __restrict__ C,
    const float* __restrict__ bias) {
  __shared__ short As[128 * 64];  // 16 KiB
  __shared__ short Bs[64 * 64];   // 8 KiB
  const int t = threadIdx.x;
  const int lane = t & 63;
  const int w = t >> 6;
  const int l16 = lane & 15;
  const int quad = lane >> 4;
  const int bm = blockIdx.x * 128;
  const int bn = blockIdx.y * 64;
  const int wm = (w & 1) * 64;
  const int wn = (w >> 1) * 32;

  const int r8 = t >> 3;
  const int swe = ((t & 7) ^ (r8 & 7)) * 8;
  const short* pA0 = A + (size_t)(bm + r8) * 1024 + swe;
  const short* pA1 = pA0 + 32 * 1024;
  const short* pA2 = pA0 + 64 * 1024;
  const short* pA3 = pA0 + 96 * 1024;
  const short* pB0 = BT + (size_t)(bn + r8) * 1024 + swe;
  const short* pB1 = pB0 + 32 * 1024;
  short* lA = As + w * 512;
  short* lB = Bs + w * 512;

  const int qsw0 = (quad ^ (l16 & 7)) * 8;
  const int qsw1 = ((quad + 4) ^ (l16 & 7)) * 8;
  const short* fA0 = As + (wm + l16) * 64 + qsw0;
  const short* fA1 = As + (wm + l16) * 64 + qsw1;
  const short* fB0 = Bs + (wn + l16) * 64 + qsw0;
  const short* fB1 = Bs + (wn + l16) * 64 + qsw1;

  f32x4 acc[4][2] = {};

  for (int it = 0; it < 16; ++it) {
    GLDS(pA0, lA); GLDS(pA1, lA + 2048); GLDS(pA2, lA + 4096); GLDS(pA3, lA + 6144);
    GLDS(pB0, lB); GLDS(pB1, lB + 2048);
    pA0 += 64; pA1 += 64; pA2 += 64; pA3 += 64;
    pB0 += 64; pB1 += 64;
    __syncthreads();

#pragma unroll
    for (int h = 0; h < 2; h++) {
      const short* fA = h ? fA1 : fA0;
      const short* fB = h ? fB1 : fB0;
      bf16x8 av[4], bw[2];
#pragma unroll
      for (int i = 0; i < 4; i++) av[i] = *(const bf16x8*)(fA + i * 1024);
#pragma unroll
      for (int j = 0; j < 2; j++) bw[j] = *(const bf16x8*)(fB + j * 1024);
#pragma unroll
      for (int i = 0; i < 4; i++)
#pragma unroll
        for (int j = 0; j < 2; j++)
          acc[i][j] = __builtin_amdgcn_mfma_f32_16x16x32_bf16(av[i], bw[j], acc[i][j], 0, 0, 0);
    }
    __syncthreads();
  }

#pragma unroll
  for (int j = 0; j < 2; j++) {
    int col = bn + wn + j * 16 + l16;
    float bl = bias[col];
#pragma unroll
    for (int i = 0; i < 4; i++)
#pragma unroll
      for (int r = 0; r < 4; r++) {
        int row = bm + wm + i * 16 + quad * 4 + r;
        C[(size_t)row * 1024 + col] = acc[i][j][r] + bl;
      }
  }
}

extern "C" void kernel_launch(void* const* d_in, const int* in_sizes, int n_in,
                              void* d_out, int out_size, void* d_ws, size_t ws_size,
                              hipStream_t stream) {
  const float* emb = (const float*)d_in[0];
  const float* Wq  = (const float*)d_in[1];
  const float* bq  = (const float*)d_in[2];
  // d_in[3]=Wk, d_in[4]=bk, d_in[7]=w are mathematically dead (they cancel)
  const float* Wv  = (const float*)d_in[5];
  const float* bv  = (const float*)d_in[6];
  const float* Wo  = (const float*)d_in[8];
  const float* bo  = (const float*)d_in[9];
  float* out = (float*)d_out;

  // workspace layout (bytes)
  char* ws = (char*)d_ws;
  short* embB = (short*)(ws);                 // 8192*1024 bf16 = 16 MiB
  short* X    = (short*)(ws + 16777216);      // 8192*1024 bf16 = 16 MiB
  short* WqvT = (short*)(ws + 33554432);      // [WqT | WvT] 2048*1024 = 4 MiB
  short* WoT  = (short*)(ws + 37748736);      // 1024*1024 = 2 MiB
  // total: 39,845,888 bytes

  prep_kernel<<<1024, 256, 0, stream>>>(emb, Wq, Wv, Wo, embB, WqvT, WoT);
  gemm_qv_kernel<<<dim3(64, 16), 256, 0, stream>>>(embB, WqvT, bq, bv, X);
  gemm_bt_kernel<<<dim3(64, 16), 256, 0, stream>>>(X, WoT, out, bo);
}

// Round 6
// 168.851 us; speedup vs baseline: 1.2042x; 1.0083x over previous
//
#include <hip/hip_runtime.h>

// Problem: B=64, S=128, D_MODEL=D_INNER=1024  ->  M = B*S = 8192, K = N = 1024.
// Reference simplifies: numerator/denominator == v exactly (dw>0, exp_k>0 cancel),
// so out = (sigmoid(emb@Wq+bq) * (emb@Wv+bv)) @ Wo + bo.  Wk, bk, w are dead inputs.
//
// R6: single-variable change vs R5 — gemm_bt 128x64 -> 128x128 tile (m103's verified
// 912 TF sweet spot), BK=64, same conflict-free swizzle, acc[4][4]/wave. Doubles
// MFMA per staged byte (32 MFMA / 8 GLDS per wave-iter, was 16/6) and halves A
// re-fetch. qv + prep untouched (R5: qv 45.7us/752TF, conflicts 0).

typedef short bf16x8 __attribute__((ext_vector_type(8)));  // 8 bf16 = 4 VGPRs
typedef float f32x4  __attribute__((ext_vector_type(4)));

__device__ __forceinline__ short f2bf(float f) {  // RNE fp32 -> bf16
  union { float f; unsigned u; } x; x.f = f;
  unsigned r = x.u + 0x7fffu + ((x.u >> 16) & 1u);
  return (short)(r >> 16);
}

struct alignas(16) S8 { short v[8]; };

#define GLDS(g, l) \
  __builtin_amdgcn_global_load_lds((const __attribute__((address_space(1))) void*)(g), \
                                   (__attribute__((address_space(3))) void*)(l), 16, 0, 0)

// ---- Phase 0: emb fp32->bf16 + transpose/cast the three 1024x1024 weights ----
__global__ __launch_bounds__(256) void prep_kernel(
    const float* __restrict__ emb, const float* __restrict__ Wq, const float* __restrict__ Wv,
    const float* __restrict__ Wo, short* __restrict__ embB, short* __restrict__ WqvT,
    short* __restrict__ WoT) {
  __shared__ float tr[32 * 33];
  const int t = threadIdx.x;
  const int bid = blockIdx.x;
  const int gdim = gridDim.x;

  // emb cast: 1048576 groups of 8
  for (size_t i = (size_t)bid * 256 + t; i < 1048576; i += (size_t)gdim * 256) {
    const float4* p = (const float4*)emb + i * 2;
    float4 a = p[0], b = p[1];
    S8 s;
    s.v[0] = f2bf(a.x); s.v[1] = f2bf(a.y); s.v[2] = f2bf(a.z); s.v[3] = f2bf(a.w);
    s.v[4] = f2bf(b.x); s.v[5] = f2bf(b.y); s.v[6] = f2bf(b.z); s.v[7] = f2bf(b.w);
    ((S8*)embB)[i] = s;
  }

  // weight transposes: 3*1024 = 3072 32x32 tiles
  int tx = t & 31, ty = t >> 5;
  for (int z = bid; z < 3072; z += gdim) {
    const float* in = (z < 1024) ? Wq : (z < 2048) ? Wv : Wo;
    short* op = (z < 1024) ? WqvT : (z < 2048) ? (WqvT + 1048576) : WoT;
    int ti = z & 1023;
    int bx = (ti & 31) * 32, by = (ti >> 5) * 32;
    __syncthreads();  // protect LDS reuse across loop iterations
#pragma unroll
    for (int i = 0; i < 32; i += 8)
      tr[(ty + i) * 33 + tx] = in[(size_t)(by + ty + i) * 1024 + bx + tx];
    __syncthreads();
#pragma unroll
    for (int i = 0; i < 32; i += 8)
      op[(size_t)(bx + ty + i) * 1024 + by + tx] = f2bf(tr[tx * 33 + ty + i]);
  }
}

// ---- Phase 1: X = sigmoid(embB@WqT+bq) * (embB@WvT+bv), bf16. BK=64. ----
// Block 128x64, 4 waves of 64x32 (q and v). grid (64,16)=1024.  [R5: 45.7us]
__global__ __launch_bounds__(256) void gemm_qv_kernel(
    const short* __restrict__ A, const short* __restrict__ BT,  // BT=[WqT|WvT] 2048x1024
    const float* __restrict__ bq, const float* __restrict__ bv, short* __restrict__ X) {
  __shared__ short As[128 * 64];  // 16 KiB
  __shared__ short Bqs[64 * 64];  // 8 KiB
  __shared__ short Bvs[64 * 64];  // 8 KiB
  const int t = threadIdx.x;
  const int lane = t & 63;
  const int w = t >> 6;
  const int l16 = lane & 15;
  const int quad = lane >> 4;
  const int bm = blockIdx.x * 128;
  const int bn = blockIdx.y * 64;
  const int wm = (w & 1) * 64;
  const int wn = (w >> 1) * 32;

  const int r8 = t >> 3;
  const int swe = ((t & 7) ^ (r8 & 7)) * 8;
  const short* pA0 = A + (size_t)(bm + r8) * 1024 + swe;
  const short* pA1 = pA0 + 32 * 1024;
  const short* pA2 = pA0 + 64 * 1024;
  const short* pA3 = pA0 + 96 * 1024;
  const short* pBq0 = BT + (size_t)(bn + r8) * 1024 + swe;
  const short* pBq1 = pBq0 + 32 * 1024;
  const short* pBv0 = BT + (size_t)(1024 + bn + r8) * 1024 + swe;
  const short* pBv1 = pBv0 + 32 * 1024;
  short* lA = As + w * 512;    // wave-uniform; HW adds lane*16B
  short* lBq = Bqs + w * 512;
  short* lBv = Bvs + w * 512;

  const int qsw0 = (quad ^ (l16 & 7)) * 8;        // k-half 0: chunk quad
  const int qsw1 = ((quad + 4) ^ (l16 & 7)) * 8;  // k-half 1: chunk quad+4
  const short* fA0 = As + (wm + l16) * 64 + qsw0;
  const short* fA1 = As + (wm + l16) * 64 + qsw1;
  const short* fq0 = Bqs + (wn + l16) * 64 + qsw0;
  const short* fq1 = Bqs + (wn + l16) * 64 + qsw1;
  const short* fv0 = Bvs + (wn + l16) * 64 + qsw0;
  const short* fv1 = Bvs + (wn + l16) * 64 + qsw1;

  f32x4 accq[4][2] = {};
  f32x4 accv[4][2] = {};

  for (int it = 0; it < 16; ++it) {
    GLDS(pA0, lA); GLDS(pA1, lA + 2048); GLDS(pA2, lA + 4096); GLDS(pA3, lA + 6144);
    GLDS(pBq0, lBq); GLDS(pBq1, lBq + 2048);
    GLDS(pBv0, lBv); GLDS(pBv1, lBv + 2048);
    pA0 += 64; pA1 += 64; pA2 += 64; pA3 += 64;
    pBq0 += 64; pBq1 += 64; pBv0 += 64; pBv1 += 64;
    __syncthreads();

#pragma unroll
    for (int h = 0; h < 2; h++) {
      const short* fA = h ? fA1 : fA0;
      const short* fq = h ? fq1 : fq0;
      const short* fv = h ? fv1 : fv0;
      bf16x8 av[4], bqf[2], bvf[2];
#pragma unroll
      for (int i = 0; i < 4; i++) av[i] = *(const bf16x8*)(fA + i * 1024);
#pragma unroll
      for (int j = 0; j < 2; j++) {
        bqf[j] = *(const bf16x8*)(fq + j * 1024);
        bvf[j] = *(const bf16x8*)(fv + j * 1024);
      }
#pragma unroll
      for (int i = 0; i < 4; i++)
#pragma unroll
        for (int j = 0; j < 2; j++) {
          accq[i][j] = __builtin_amdgcn_mfma_f32_16x16x32_bf16(av[i], bqf[j], accq[i][j], 0, 0, 0);
          accv[i][j] = __builtin_amdgcn_mfma_f32_16x16x32_bf16(av[i], bvf[j], accv[i][j], 0, 0, 0);
        }
    }
    __syncthreads();
  }

  // epilogue: C/D layout col=lane&15, row=(lane>>4)*4+reg  [m89/m91-verified]
#pragma unroll
  for (int j = 0; j < 2; j++) {
    int col = bn + wn + j * 16 + l16;
    float bql = bq[col], bvl = bv[col];
#pragma unroll
    for (int i = 0; i < 4; i++)
#pragma unroll
      for (int r = 0; r < 4; r++) {
        int row = bm + wm + i * 16 + quad * 4 + r;
        float q = accq[i][j][r] + bql;
        float v = accv[i][j][r] + bvl;
        float s = 1.0f / (1.0f + __expf(-q));
        X[(size_t)row * 1024 + col] = f2bf(s * v);
      }
  }
}

// ---- Phase 2: out = X @ WoT^T + bo, fp32. R6: 128x128 tile, BK=64, grid (64,8). ----
// 4 waves in 2x2; each wave 64x64 via acc[4][4]. 32 MFMA / 8 GLDS per wave-iter.
__global__ __launch_bounds__(256) void gemm_bt_kernel(
    const short* __restrict__ A, const short* __restrict__ BT, float* __restrict__ C,
    const float* __restrict__ bias) {
  __shared__ short As[128 * 64];  // 16 KiB
  __shared__ short Bs[128 * 64];  // 16 KiB
  const int t = threadIdx.x;
  const int lane = t & 63;
  const int w = t >> 6;
  const int l16 = lane & 15;
  const int quad = lane >> 4;
  const int bm = blockIdx.x * 128;
  const int bn = blockIdx.y * 128;
  const int wm = (w & 1) * 64;
  const int wn = (w >> 1) * 64;

  const int r8 = t >> 3;
  const int swe = ((t & 7) ^ (r8 & 7)) * 8;
  const short* pA0 = A + (size_t)(bm + r8) * 1024 + swe;
  const short* pA1 = pA0 + 32 * 1024;
  const short* pA2 = pA0 + 64 * 1024;
  const short* pA3 = pA0 + 96 * 1024;
  const short* pB0 = BT + (size_t)(bn + r8) * 1024 + swe;
  const short* pB1 = pB0 + 32 * 1024;
  const short* pB2 = pB0 + 64 * 1024;
  const short* pB3 = pB0 + 96 * 1024;
  short* lA = As + w * 512;
  short* lB = Bs + w * 512;

  const int qsw0 = (quad ^ (l16 & 7)) * 8;
  const int qsw1 = ((quad + 4) ^ (l16 & 7)) * 8;
  const short* fA0 = As + (wm + l16) * 64 + qsw0;
  const short* fA1 = As + (wm + l16) * 64 + qsw1;
  const short* fB0 = Bs + (wn + l16) * 64 + qsw0;
  const short* fB1 = Bs + (wn + l16) * 64 + qsw1;

  f32x4 acc[4][4] = {};

  for (int it = 0; it < 16; ++it) {
    GLDS(pA0, lA); GLDS(pA1, lA + 2048); GLDS(pA2, lA + 4096); GLDS(pA3, lA + 6144);
    GLDS(pB0, lB); GLDS(pB1, lB + 2048); GLDS(pB2, lB + 4096); GLDS(pB3, lB + 6144);
    pA0 += 64; pA1 += 64; pA2 += 64; pA3 += 64;
    pB0 += 64; pB1 += 64; pB2 += 64; pB3 += 64;
    __syncthreads();

#pragma unroll
    for (int h = 0; h < 2; h++) {
      const short* fA = h ? fA1 : fA0;
      const short* fB = h ? fB1 : fB0;
      bf16x8 av[4], bw[4];
#pragma unroll
      for (int i = 0; i < 4; i++) av[i] = *(const bf16x8*)(fA + i * 1024);
#pragma unroll
      for (int j = 0; j < 4; j++) bw[j] = *(const bf16x8*)(fB + j * 1024);
#pragma unroll
      for (int i = 0; i < 4; i++)
#pragma unroll
        for (int j = 0; j < 4; j++)
          acc[i][j] = __builtin_amdgcn_mfma_f32_16x16x32_bf16(av[i], bw[j], acc[i][j], 0, 0, 0);
    }
    __syncthreads();
  }

#pragma unroll
  for (int j = 0; j < 4; j++) {
    int col = bn + wn + j * 16 + l16;
    float bl = bias[col];
#pragma unroll
    for (int i = 0; i < 4; i++)
#pragma unroll
      for (int r = 0; r < 4; r++) {
        int row = bm + wm + i * 16 + quad * 4 + r;
        C[(size_t)row * 1024 + col] = acc[i][j][r] + bl;
      }
  }
}

extern "C" void kernel_launch(void* const* d_in, const int* in_sizes, int n_in,
                              void* d_out, int out_size, void* d_ws, size_t ws_size,
                              hipStream_t stream) {
  const float* emb = (const float*)d_in[0];
  const float* Wq  = (const float*)d_in[1];
  const float* bq  = (const float*)d_in[2];
  // d_in[3]=Wk, d_in[4]=bk, d_in[7]=w are mathematically dead (they cancel)
  const float* Wv  = (const float*)d_in[5];
  const float* bv  = (const float*)d_in[6];
  const float* Wo  = (const float*)d_in[8];
  const float* bo  = (const float*)d_in[9];
  float* out = (float*)d_out;

  // workspace layout (bytes)
  char* ws = (char*)d_ws;
  short* embB = (short*)(ws);                 // 8192*1024 bf16 = 16 MiB
  short* X    = (short*)(ws + 16777216);      // 8192*1024 bf16 = 16 MiB
  short* WqvT = (short*)(ws + 33554432);      // [WqT | WvT] 2048*1024 = 4 MiB
  short* WoT  = (short*)(ws + 37748736);      // 1024*1024 = 2 MiB
  // total: 39,845,888 bytes

  prep_kernel<<<1024, 256, 0, stream>>>(emb, Wq, Wv, Wo, embB, WqvT, WoT);
  gemm_qv_kernel<<<dim3(64, 16), 256, 0, stream>>>(embB, WqvT, bq, bv, X);
  gemm_bt_kernel<<<dim3(64, 8), 256, 0, stream>>>(X, WoT, out, bo);
}